// Round 7
// baseline (158.150 us; speedup 1.0000x reference)
//
#include <hip/hip_runtime.h>
#include <hip/hip_bf16.h>

// Problem dims (fixed by the reference): B=64, T=2048, D=256
#define BB  64
#define TT  2048
#define DD  256
#define EPSV 1e-7f
#define TILE_R 32   // rows per tile
#define NTILE  8    // tiles per block
#define NBLK   512  // blocks: NBLK*NTILE*TILE_R == BB*TT ; 2 blocks/CU

typedef __attribute__((ext_vector_type(8))) short bf16x8;   // MFMA A/B fragment (4 VGPR)
typedef __attribute__((ext_vector_type(4))) float f32x4;    // MFMA C/D fragment

__device__ __forceinline__ ushort f2bf(float f) {           // RNE
    union { float f; unsigned u; } v; v.f = f;
    unsigned u = v.u;
    unsigned r = (u + 0x7FFFu + ((u >> 16) & 1u)) >> 16;
    return (ushort)r;
}

__device__ __forceinline__ float bf2f(unsigned h16) {       // low 16 bits = bf16
    union { unsigned u; float f; } v; v.u = h16 << 16;
    return v.f;
}

// pack two f32 -> two bf16 (round-half-up): [bf(lo), bf(hi)]
__device__ __forceinline__ unsigned pkbf(float lo, float hi) {
    union { float f; unsigned u; } a, b;
    a.f = lo; b.f = hi;
    return __builtin_amdgcn_perm(b.u + 0x8000u, a.u + 0x8000u, 0x07060302u);
}

__device__ __forceinline__ float tanh_fast(float x) {
    float e = __expf(2.0f * x);
    return 1.0f - 2.0f * __builtin_amdgcn_rcpf(e + 1.0f);
}

// sum over the 16-lane DPP row via rotations (pure VALU, no LDS traffic)
template<int CTRL>
__device__ __forceinline__ float dpp_rot_add(float x) {
    union { float f; int i; } a; a.f = x;
    int r = __builtin_amdgcn_update_dpp(0, a.i, CTRL, 0xF, 0xF, true);
    union { int i; float f; } b; b.i = r;
    return x + b.f;
}
__device__ __forceinline__ float row16_sum(float x) {
    x = dpp_rot_add<0x121>(x);   // row_ror:1
    x = dpp_rot_add<0x122>(x);   // row_ror:2
    x = dpp_rot_add<0x124>(x);   // row_ror:4
    x = dpp_rot_add<0x128>(x);   // row_ror:8
    return x;                    // all 16 lanes hold the row sum
}

// ---------------------------------------------------------------------------
// attn_main: 512 blocks x 512 thr (8 waves), 8 tiles of 32 rows.
// Self-contained: prologue gathers Bf straight from fp32 context_w (L2-hot)
// and computes this block's bias row in-block (no prep kernel).
// Triple-buffered bf16 tiles -> ONE barrier per tile. Per iter:
//   [convert(it+1) | issue loads(it+2) | GEMM(it) | tanh+gpartT] BAR [evals | wsum]
// launch_bounds(512,4): VGPR cap 128 (audit ~117) -> 2 blocks/CU guaranteed.
// ---------------------------------------------------------------------------
__global__ __launch_bounds__(512, 4) void attn_main(
    const float* __restrict__ ctx, const int* __restrict__ mask,
    const float* __restrict__ attend_w,
    const float* __restrict__ aspect, const float* __restrict__ sentence,
    const float* __restrict__ context_w, const float* __restrict__ aspect_w,
    const float* __restrict__ sent_w,
    float* __restrict__ partial_ws, float* __restrict__ esum_ws)
{
    __shared__ __align__(16) char bfb[3][TILE_R * 512];  // 3 x 16KB, 512B pitch, XOR swizzle
    __shared__ float gpartT[2][8][TILE_R];               // [phase][cg][row]
    __shared__ float bias_half[2][256];
    __shared__ float aw_lds[256];
    __shared__ float mask_lds[256];
    __shared__ float part_d[8][256];

    const int tid  = threadIdx.x;
    const int wave = tid >> 6;
    const int lane = tid & 63;
    const int blk  = blockIdx.x;
    const int b    = blk >> 3;               // 8 blocks per batch element
    const int cg   = wave;                   // col group (32 cols)
    const int l15  = lane & 15, hi = lane >> 4;

    const float4* src = reinterpret_cast<const float4*>(ctx);
    const int cc  = tid;                     // 8-float chunk index base
    const int crow0 = cc >> 5,         c80 = cc & 31;
    const int crow1 = (512 + cc) >> 5, c81 = (512 + cc) & 31;

    // ---- (P1) issue tile 0 global loads ----
    float4 sreg[4];
    {
        const size_t base4 = (size_t)(blk * NTILE) * 2048;
        #pragma unroll
        for (int i = 0; i < 2; ++i) {
            const int c = i * 512 + tid;
            sreg[2 * i + 0] = src[base4 + 2 * c + 0];
            sreg[2 * i + 1] = src[base4 + 2 * c + 1];
        }
    }

    // ---- (P2) Bf gather: fp32 context_w -> bf16 MFMA B-frags (this wave's 32 cols) ----
    bf16x8 Bf[8][2];
    #pragma unroll
    for (int kk = 0; kk < 8; ++kk) {
        #pragma unroll
        for (int n2 = 0; n2 < 2; ++n2) {
            const int col  = (cg * 2 + n2) * 16 + l15;
            const int krow = kk * 32 + hi * 8;
            const float* wp = context_w + (size_t)krow * DD + col;
            bf16x8 v;
            #pragma unroll
            for (int j = 0; j < 8; ++j)
                v[j] = (short)f2bf(wp[j * DD]);
            Bf[kk][n2] = v;
        }
    }

    // ---- (P3) aux loads + in-block bias GEMV (halves over d) ----
    if (tid < 256) {
        aw_lds[tid]   = attend_w[tid];
        mask_lds[tid] = (float)mask[blk * 256 + tid];
    }
    {
        const int e = tid & 255, h = tid >> 8;
        const float* ap = aspect   + b * DD + h * 128;
        const float* sp = sentence + b * DD + h * 128;
        const float* awp = aspect_w + (size_t)(h * 128) * DD + e;
        const float* swp = sent_w   + (size_t)(h * 128) * DD + e;
        float bsum = 0.f;
        #pragma unroll 4
        for (int dd = 0; dd < 128; ++dd) {
            bsum = fmaf(ap[dd], awp[(size_t)dd * DD], bsum);
            bsum = fmaf(sp[dd], swp[(size_t)dd * DD], bsum);
        }
        bias_half[h][e] = bsum;
    }

    // ---- (P4) convert tile 0 -> buf0, issue tile 1 ----
    {
        char* dst = bfb[0];
        #pragma unroll
        for (int i = 0; i < 2; ++i) {
            const int row = i ? crow1 : crow0, c8 = i ? c81 : c80;
            uint4 u;
            u.x = pkbf(sreg[2 * i].x,     sreg[2 * i].y);
            u.y = pkbf(sreg[2 * i].z,     sreg[2 * i].w);
            u.z = pkbf(sreg[2 * i + 1].x, sreg[2 * i + 1].y);
            u.w = pkbf(sreg[2 * i + 1].z, sreg[2 * i + 1].w);
            *reinterpret_cast<uint4*>(dst + row * 512 + ((c8 * 16) ^ ((row & 7) << 4))) = u;
        }
        const size_t b1 = (size_t)(blk * NTILE + 1) * 2048;
        #pragma unroll
        for (int i = 0; i < 2; ++i) {
            const int c = i * 512 + tid;
            sreg[2 * i + 0] = src[b1 + 2 * c + 0];
            sreg[2 * i + 1] = src[b1 + 2 * c + 1];
        }
    }
    __syncthreads();

    // loop-invariant epilogue constants (after barrier: bias_half complete)
    const int c0 = cg * 32 + l15, c1 = c0 + 16;
    const float bs0 = bias_half[0][c0] + bias_half[1][c0], awc0 = aw_lds[c0];
    const float bs1 = bias_half[0][c1] + bias_half[1][c1], awc1 = aw_lds[c1];

    float accd[4] = {0.f, 0.f, 0.f, 0.f};
    float es_acc = 0.f;
    int cb = 0;

    for (int it = 0; it < NTILE; ++it) {
        const int nb = (cb == 2) ? 0 : cb + 1;
        const int gp = it & 1;
        const char* lb = bfb[cb];

        // ---- (1) convert sreg (tile it+1 data) -> buf nb ----
        if (it + 1 < NTILE) {
            char* dst = bfb[nb];
            #pragma unroll
            for (int i = 0; i < 2; ++i) {
                const int row = i ? crow1 : crow0, c8 = i ? c81 : c80;
                uint4 u;
                u.x = pkbf(sreg[2 * i].x,     sreg[2 * i].y);
                u.y = pkbf(sreg[2 * i].z,     sreg[2 * i].w);
                u.z = pkbf(sreg[2 * i + 1].x, sreg[2 * i + 1].y);
                u.w = pkbf(sreg[2 * i + 1].z, sreg[2 * i + 1].w);
                *reinterpret_cast<uint4*>(dst + row * 512 + ((c8 * 16) ^ ((row & 7) << 4))) = u;
            }
        }
        // ---- (2) issue tile it+2 global loads ----
        if (it + 2 < NTILE) {
            const size_t base4 = (size_t)(blk * NTILE + it + 2) * 2048;
            #pragma unroll
            for (int i = 0; i < 2; ++i) {
                const int c = i * 512 + tid;
                sreg[2 * i + 0] = src[base4 + 2 * c + 0];
                sreg[2 * i + 1] = src[base4 + 2 * c + 1];
            }
        }

        // ---- (3) GEMM: 32 rows x this wave's 32 cols, K=256 ----
        f32x4 acc[2][2];
        #pragma unroll
        for (int rt = 0; rt < 2; ++rt) {
            acc[rt][0] = (f32x4){0.f, 0.f, 0.f, 0.f};
            acc[rt][1] = (f32x4){0.f, 0.f, 0.f, 0.f};
        }
        #pragma unroll
        for (int rt = 0; rt < 2; ++rt) {
            const int row = rt * 16 + l15;
            const char* ab = lb + row * 512;
            const int asw = (row & 7) << 4;
            #pragma unroll
            for (int kk = 0; kk < 8; ++kk) {
                const bf16x8 a = *reinterpret_cast<const bf16x8*>(
                    ab + ((kk * 64 + (hi << 4)) ^ asw));
                acc[rt][0] = __builtin_amdgcn_mfma_f32_16x16x32_bf16(a, Bf[kk][0], acc[rt][0], 0, 0, 0);
                acc[rt][1] = __builtin_amdgcn_mfma_f32_16x16x32_bf16(a, Bf[kk][1], acc[rt][1], 0, 0, 0);
            }
        }

        // ---- (4) tanh epilogue + DPP reduce -> gpartT[gp][cg][*] ----
        #pragma unroll
        for (int rt = 0; rt < 2; ++rt) {
            float g0 = row16_sum(tanh_fast(acc[rt][0][0] + bs0) * awc0
                               + tanh_fast(acc[rt][1][0] + bs1) * awc1);
            float g1 = row16_sum(tanh_fast(acc[rt][0][1] + bs0) * awc0
                               + tanh_fast(acc[rt][1][1] + bs1) * awc1);
            float g2 = row16_sum(tanh_fast(acc[rt][0][2] + bs0) * awc0
                               + tanh_fast(acc[rt][1][2] + bs1) * awc1);
            float g3 = row16_sum(tanh_fast(acc[rt][0][3] + bs0) * awc0
                               + tanh_fast(acc[rt][1][3] + bs1) * awc1);
            if (l15 == 0) {
                const int r = rt * 16 + (hi << 2);
                *reinterpret_cast<float4*>(&gpartT[gp][cg][r]) = (float4){g0, g1, g2, g3};
            }
        }
        __syncthreads();   // the ONLY barrier per tile

        // ---- (5) evals: every lane computes ev for row lane&31 ----
        const int erow = lane & 31;
        float gsum = 0.f;
        #pragma unroll
        for (int c = 0; c < 8; ++c) gsum += gpartT[gp][c][erow];
        const float ev = __expf(gsum) * mask_lds[it * TILE_R + erow];
        es_acc += (lane < 32) ? ev : 0.f;

        // ---- (6) fused weighted sum: wave handles tile rows wave*4..+3 ----
        #pragma unroll
        for (int rr = 0; rr < 4; ++rr) {
            const int r = wave * 4 + rr;
            const float e = __shfl(ev, r);   // uniform index -> readlane broadcast
            const uint2 hv = *reinterpret_cast<const uint2*>(
                lb + r * 512 + ((lane * 8) ^ ((r & 7) << 4)));
            accd[0] = fmaf(bf2f(hv.x & 0xffffu), e, accd[0]);
            accd[1] = fmaf(bf2f(hv.x >> 16),     e, accd[1]);
            accd[2] = fmaf(bf2f(hv.y & 0xffffu), e, accd[2]);
            accd[3] = fmaf(bf2f(hv.y >> 16),     e, accd[3]);
        }

        cb = nb;
    }

    // ---- block epilogue ----
    *reinterpret_cast<float4*>(&part_d[wave][lane * 4]) =
        (float4){accd[0], accd[1], accd[2], accd[3]};
    __syncthreads();
    if (tid < 256) {
        float s = 0.f;
        #pragma unroll
        for (int w = 0; w < 8; ++w) s += part_d[w][tid];
        partial_ws[blk * DD + tid] = s;
    }
    if (wave == 0) {
        float s = row16_sum(es_acc);
        s += __shfl_xor(s, 16);
        if (lane == 0) esum_ws[blk] = s;
    }
}

// ---------------------------------------------------------------------------
// finalize: out[b,d] = (sum_i partial) / (sum_i esum + EPS) + sentence[b,d]
// ---------------------------------------------------------------------------
__global__ __launch_bounds__(256) void finalize_kernel(
    const float* __restrict__ sentence, const float* __restrict__ partial_ws,
    const float* __restrict__ esum_ws, float* __restrict__ out)
{
    const int b = blockIdx.x, d = threadIdx.x;
    float es = 0.f, s = 0.f;
    #pragma unroll
    for (int i = 0; i < 8; ++i) {
        es += esum_ws[b * 8 + i];
        s  += partial_ws[(size_t)(b * 8 + i) * DD + d];
    }
    out[b * DD + d] = s / (es + EPSV) + sentence[b * DD + d];
}

extern "C" void kernel_launch(void* const* d_in, const int* in_sizes, int n_in,
                              void* d_out, int out_size, void* d_ws, size_t ws_size,
                              hipStream_t stream)
{
    const float* ctx       = (const float*)d_in[0];
    const float* aspect    = (const float*)d_in[1];
    const float* sentence  = (const float*)d_in[2];
    const int*   mask      = (const int*)  d_in[3];
    const float* context_w = (const float*)d_in[4];
    const float* aspect_w  = (const float*)d_in[5];
    const float* sent_w    = (const float*)d_in[6];
    const float* attend_w  = (const float*)d_in[7];
    float* out = (float*)d_out;

    char* ws = (char*)d_ws;
    float* esum_ws    = (float*)(ws);            //   2048 B
    float* partial_ws = (float*)(ws + 2048);     // 524288 B

    attn_main<<<NBLK, 512, 0, stream>>>(ctx, mask, attend_w, aspect, sentence,
                                        context_w, aspect_w, sent_w,
                                        partial_ws, esum_ws);
    finalize_kernel<<<BB, 256, 0, stream>>>(sentence, partial_ws, esum_ws, out);
}

// Round 8
// 48.330 us; speedup vs baseline: 3.2723x; 3.2723x over previous
//
#include <hip/hip_runtime.h>
#include <hip/hip_bf16.h>

// Problem dims (fixed by the reference): B=64, T=2048, D=256
#define BB  64
#define TT  2048
#define DD  256
#define EPSV 1e-7f
#define TILE_R 32   // rows per tile
#define NTILE  8    // tiles per block
#define NBLK   512  // blocks: NBLK*NTILE*TILE_R == BB*TT

typedef __attribute__((ext_vector_type(8))) short bf16x8;   // MFMA A/B fragment (4 VGPR)
typedef __attribute__((ext_vector_type(4))) float f32x4;    // MFMA C/D fragment

__device__ __forceinline__ ushort f2bf(float f) {           // RNE (prep only)
    union { float f; unsigned u; } v; v.f = f;
    unsigned u = v.u;
    unsigned r = (u + 0x7FFFu + ((u >> 16) & 1u)) >> 16;
    return (ushort)r;
}

__device__ __forceinline__ float bf2f(unsigned h16) {       // low 16 bits = bf16
    union { unsigned u; float f; } v; v.u = h16 << 16;
    return v.f;
}

// pack two f32 -> two bf16 (round-half-up): [bf(lo), bf(hi)]
__device__ __forceinline__ unsigned pkbf(float lo, float hi) {
    union { float f; unsigned u; } a, b;
    a.f = lo; b.f = hi;
    return __builtin_amdgcn_perm(b.u + 0x8000u, a.u + 0x8000u, 0x07060302u);
}

__device__ __forceinline__ float tanh_fast(float x) {
    float e = __expf(2.0f * x);
    return 1.0f - 2.0f * __builtin_amdgcn_rcpf(e + 1.0f);
}

// sum over the 16-lane DPP row via rotations (pure VALU, no LDS traffic)
template<int CTRL>
__device__ __forceinline__ float dpp_rot_add(float x) {
    union { float f; int i; } a; a.f = x;
    int r = __builtin_amdgcn_update_dpp(0, a.i, CTRL, 0xF, 0xF, true);
    union { int i; float f; } b; b.i = r;
    return x + b.f;
}
__device__ __forceinline__ float row16_sum(float x) {
    x = dpp_rot_add<0x121>(x);   // row_ror:1
    x = dpp_rot_add<0x122>(x);   // row_ror:2
    x = dpp_rot_add<0x124>(x);   // row_ror:4
    x = dpp_rot_add<0x128>(x);   // row_ror:8
    return x;                    // all 16 lanes hold the row sum
}

// ---------------------------------------------------------------------------
// prep: blocks 0..511   -> bias partials (block b*8+q covers d in [q*32, q*32+32))
//       blocks 512..543 -> W_frag: context_w (f32 [256][256]) -> bf16 MFMA B-frag order
// ---------------------------------------------------------------------------
__global__ __launch_bounds__(256) void prep_kernel(
    const float* __restrict__ aspect, const float* __restrict__ sentence,
    const float* __restrict__ context_w, const float* __restrict__ aspect_w,
    const float* __restrict__ sent_w,
    float* __restrict__ bias_part, ushort* __restrict__ wfrag_ws)
{
    const int blk = blockIdx.x, tid = threadIdx.x;
    if (blk < 512) {
        const int b = blk >> 3, q = blk & 7, e = tid;
        float s = 0.f;
        #pragma unroll 4
        for (int dd = 0; dd < 32; ++dd) {
            const int d = q * 32 + dd;
            s = fmaf(aspect[b * DD + d],   aspect_w[d * DD + e], s);
            s = fmaf(sentence[b * DD + d], sent_w[d * DD + e],   s);
        }
        bias_part[blk * DD + e] = s;
    } else {
        const int flat = (blk - 512) * 256 + tid;    // 0..8191
        const int lane = flat & 63;
        const int kn   = flat >> 6;
        const int kk   = kn >> 4;
        const int n    = kn & 15;
        const int krow = kk * 32 + ((lane >> 4) << 3);
        const int col  = n * 16 + (lane & 15);
        bf16x8 v;
        #pragma unroll
        for (int j = 0; j < 8; ++j)
            v[j] = (short)f2bf(context_w[(size_t)(krow + j) * DD + col]);
        *reinterpret_cast<bf16x8*>(wfrag_ws + (size_t)flat * 8) = v;
    }
}

// ---------------------------------------------------------------------------
// attn_main: 512 blocks x 512 thr (8 waves), 8 tiles of 32 rows.
// QUAD-buffered bf16 tiles, ONE barrier per tile, and evals+wsum DEFERRED by
// one iteration so the whole barrier period is mutually independent work:
//   [wsum(it-1) | convert(it+1) | loads(it+2) | GEMM(it) | tanh->gpartT] BAR
// Buffer recycle: convert(it+1) -> buf[(it+1)&3]; prior readers GEMM(it-3)
// (3 BARs ago) and wsum(it-3) in iter it-2 (>=1 BAR ago). gpartT[it&1]:
// written iter it, read iter it+1, rewritten iter it+2 (1 BAR each side).
// ---------------------------------------------------------------------------
__global__ __launch_bounds__(512, 2) void attn_main(
    const float* __restrict__ ctx, const int* __restrict__ mask,
    const float* __restrict__ attend_w,
    const float* __restrict__ bias_part, const ushort* __restrict__ wfrag_ws,
    float* __restrict__ partial_ws, float* __restrict__ esum_ws)
{
    __shared__ __align__(16) char bfb[4][TILE_R * 512];  // 4 x 16KB, 512B pitch, XOR swizzle
    __shared__ float gpartT[2][8][TILE_R];               // [phase][cg][row]
    __shared__ float bias_lds[256];
    __shared__ float aw_lds[256];
    __shared__ float mask_lds[256];
    __shared__ float part_d[8][256];

    const int tid  = threadIdx.x;
    const int wave = tid >> 6;
    const int lane = tid & 63;
    const int blk  = blockIdx.x;
    const int b    = blk >> 3;               // 8 blocks per batch element
    const int cg   = wave;                   // col group (32 cols)
    const int l15  = lane & 15, hi = lane >> 4;

    if (tid < 256) {
        float bs = 0.f;
        #pragma unroll
        for (int q = 0; q < 8; ++q) bs += bias_part[(b * 8 + q) * DD + tid];
        bias_lds[tid] = bs;
    } else {
        const int m = tid - 256;
        aw_lds[m]   = attend_w[m];
        mask_lds[m] = (float)mask[blk * 256 + m];
    }

    // ---- preload this wave's 16 B-fragments (cols cg*32 .. +31): 64 VGPR ----
    bf16x8 Bf[8][2];
    {
        const bf16x8* wf = reinterpret_cast<const bf16x8*>(wfrag_ws);
        #pragma unroll
        for (int kk = 0; kk < 8; ++kk) {
            Bf[kk][0] = wf[(kk * 16 + cg * 2 + 0) * 64 + lane];
            Bf[kk][1] = wf[(kk * 16 + cg * 2 + 1) * 64 + lane];
        }
    }

    const float4* src = reinterpret_cast<const float4*>(ctx);
    const int cc  = tid;                     // 8-float chunk index base
    const int crow0 = cc >> 5,         c80 = cc & 31;
    const int crow1 = (512 + cc) >> 5, c81 = (512 + cc) & 31;

    // ---- prologue: load tile 0, convert -> buf0, issue tile 1 loads ----
    float4 sreg[4];
    {
        const size_t base4 = (size_t)(blk * NTILE) * 2048;
        #pragma unroll
        for (int i = 0; i < 2; ++i) {
            const int c = i * 512 + tid;
            sreg[2 * i + 0] = src[base4 + 2 * c + 0];
            sreg[2 * i + 1] = src[base4 + 2 * c + 1];
        }
        char* dst = bfb[0];
        #pragma unroll
        for (int i = 0; i < 2; ++i) {
            const int row = i ? crow1 : crow0, c8 = i ? c81 : c80;
            uint4 u;
            u.x = pkbf(sreg[2 * i].x,     sreg[2 * i].y);
            u.y = pkbf(sreg[2 * i].z,     sreg[2 * i].w);
            u.z = pkbf(sreg[2 * i + 1].x, sreg[2 * i + 1].y);
            u.w = pkbf(sreg[2 * i + 1].z, sreg[2 * i + 1].w);
            *reinterpret_cast<uint4*>(dst + row * 512 + ((c8 * 16) ^ ((row & 7) << 4))) = u;
        }
        const size_t b1 = (size_t)(blk * NTILE + 1) * 2048;
        #pragma unroll
        for (int i = 0; i < 2; ++i) {
            const int c = i * 512 + tid;
            sreg[2 * i + 0] = src[b1 + 2 * c + 0];
            sreg[2 * i + 1] = src[b1 + 2 * c + 1];
        }
    }
    __syncthreads();

    // loop-invariant epilogue constants
    const int c0 = cg * 32 + l15, c1 = c0 + 16;
    const float bs0 = bias_lds[c0], awc0 = aw_lds[c0];
    const float bs1 = bias_lds[c1], awc1 = aw_lds[c1];

    float accd[4] = {0.f, 0.f, 0.f, 0.f};
    float es_acc = 0.f;

    // deferred evals + weighted sum for tile t (reads gpartT[t&1], bfb[t&3])
    auto do_wsum = [&](int t) {
        const char* pb = bfb[t & 3];
        const int gp = t & 1;
        const int erow = lane & 31;
        float gsum = 0.f;
        #pragma unroll
        for (int c = 0; c < 8; ++c) gsum += gpartT[gp][c][erow];
        const float ev = __expf(gsum) * mask_lds[t * TILE_R + erow];
        es_acc += (lane < 32) ? ev : 0.f;
        #pragma unroll
        for (int rr = 0; rr < 4; ++rr) {
            const int r = wave * 4 + rr;
            const float e = __shfl(ev, r);   // uniform index -> readlane broadcast
            const uint2 hv = *reinterpret_cast<const uint2*>(
                pb + r * 512 + ((lane * 8) ^ ((r & 7) << 4)));
            accd[0] = fmaf(bf2f(hv.x & 0xffffu), e, accd[0]);
            accd[1] = fmaf(bf2f(hv.x >> 16),     e, accd[1]);
            accd[2] = fmaf(bf2f(hv.y & 0xffffu), e, accd[2]);
            accd[3] = fmaf(bf2f(hv.y >> 16),     e, accd[3]);
        }
    };

    for (int it = 0; it < NTILE; ++it) {
        const char* lb = bfb[it & 3];

        // ---- (0) deferred evals+wsum for tile it-1 (independent of this phase) ----
        if (it > 0) do_wsum(it - 1);

        // ---- (1) convert sreg (tile it+1 data) -> buf[(it+1)&3] ----
        if (it + 1 < NTILE) {
            char* dst = bfb[(it + 1) & 3];
            #pragma unroll
            for (int i = 0; i < 2; ++i) {
                const int row = i ? crow1 : crow0, c8 = i ? c81 : c80;
                uint4 u;
                u.x = pkbf(sreg[2 * i].x,     sreg[2 * i].y);
                u.y = pkbf(sreg[2 * i].z,     sreg[2 * i].w);
                u.z = pkbf(sreg[2 * i + 1].x, sreg[2 * i + 1].y);
                u.w = pkbf(sreg[2 * i + 1].z, sreg[2 * i + 1].w);
                *reinterpret_cast<uint4*>(dst + row * 512 + ((c8 * 16) ^ ((row & 7) << 4))) = u;
            }
        }
        // ---- (2) issue tile it+2 global loads ----
        if (it + 2 < NTILE) {
            const size_t base4 = (size_t)(blk * NTILE + it + 2) * 2048;
            #pragma unroll
            for (int i = 0; i < 2; ++i) {
                const int c = i * 512 + tid;
                sreg[2 * i + 0] = src[base4 + 2 * c + 0];
                sreg[2 * i + 1] = src[base4 + 2 * c + 1];
            }
        }

        // ---- (3) GEMM: 32 rows x this wave's 32 cols, K=256 ----
        f32x4 acc[2][2];
        #pragma unroll
        for (int rt = 0; rt < 2; ++rt) {
            acc[rt][0] = (f32x4){0.f, 0.f, 0.f, 0.f};
            acc[rt][1] = (f32x4){0.f, 0.f, 0.f, 0.f};
        }
        __builtin_amdgcn_s_setprio(1);
        #pragma unroll
        for (int rt = 0; rt < 2; ++rt) {
            const int row = rt * 16 + l15;
            const char* ab = lb + row * 512;
            const int asw = (row & 7) << 4;
            #pragma unroll
            for (int kk = 0; kk < 8; ++kk) {
                const bf16x8 a = *reinterpret_cast<const bf16x8*>(
                    ab + ((kk * 64 + (hi << 4)) ^ asw));
                acc[rt][0] = __builtin_amdgcn_mfma_f32_16x16x32_bf16(a, Bf[kk][0], acc[rt][0], 0, 0, 0);
                acc[rt][1] = __builtin_amdgcn_mfma_f32_16x16x32_bf16(a, Bf[kk][1], acc[rt][1], 0, 0, 0);
            }
        }
        __builtin_amdgcn_s_setprio(0);

        // ---- (4) tanh epilogue + DPP reduce -> gpartT[it&1][cg][*] ----
        const int gp = it & 1;
        #pragma unroll
        for (int rt = 0; rt < 2; ++rt) {
            float g0 = row16_sum(tanh_fast(acc[rt][0][0] + bs0) * awc0
                               + tanh_fast(acc[rt][1][0] + bs1) * awc1);
            float g1 = row16_sum(tanh_fast(acc[rt][0][1] + bs0) * awc0
                               + tanh_fast(acc[rt][1][1] + bs1) * awc1);
            float g2 = row16_sum(tanh_fast(acc[rt][0][2] + bs0) * awc0
                               + tanh_fast(acc[rt][1][2] + bs1) * awc1);
            float g3 = row16_sum(tanh_fast(acc[rt][0][3] + bs0) * awc0
                               + tanh_fast(acc[rt][1][3] + bs1) * awc1);
            if (l15 == 0) {
                const int r = rt * 16 + (hi << 2);
                *reinterpret_cast<float4*>(&gpartT[gp][cg][r]) = (float4){g0, g1, g2, g3};
            }
        }
        __syncthreads();   // the ONLY barrier per tile
    }

    // ---- drain: evals+wsum for the last tile ----
    do_wsum(NTILE - 1);

    // ---- block epilogue ----
    *reinterpret_cast<float4*>(&part_d[wave][lane * 4]) =
        (float4){accd[0], accd[1], accd[2], accd[3]};
    __syncthreads();
    if (tid < 256) {
        float s = 0.f;
        #pragma unroll
        for (int w = 0; w < 8; ++w) s += part_d[w][tid];
        partial_ws[blk * DD + tid] = s;
    }
    if (wave == 0) {
        float s = row16_sum(es_acc);
        s += __shfl_xor(s, 16);
        if (lane == 0) esum_ws[blk] = s;
    }
}

// ---------------------------------------------------------------------------
// finalize: out[b,d] = (sum_i partial) / (sum_i esum + EPS) + sentence[b,d]
// ---------------------------------------------------------------------------
__global__ __launch_bounds__(256) void finalize_kernel(
    const float* __restrict__ sentence, const float* __restrict__ partial_ws,
    const float* __restrict__ esum_ws, float* __restrict__ out)
{
    const int b = blockIdx.x, d = threadIdx.x;
    float es = 0.f, s = 0.f;
    #pragma unroll
    for (int i = 0; i < 8; ++i) {
        es += esum_ws[b * 8 + i];
        s  += partial_ws[(size_t)(b * 8 + i) * DD + d];
    }
    out[b * DD + d] = s / (es + EPSV) + sentence[b * DD + d];
}

extern "C" void kernel_launch(void* const* d_in, const int* in_sizes, int n_in,
                              void* d_out, int out_size, void* d_ws, size_t ws_size,
                              hipStream_t stream)
{
    const float* ctx       = (const float*)d_in[0];
    const float* aspect    = (const float*)d_in[1];
    const float* sentence  = (const float*)d_in[2];
    const int*   mask      = (const int*)  d_in[3];
    const float* context_w = (const float*)d_in[4];
    const float* aspect_w  = (const float*)d_in[5];
    const float* sent_w    = (const float*)d_in[6];
    const float* attend_w  = (const float*)d_in[7];
    float* out = (float*)d_out;

    char* ws = (char*)d_ws;
    ushort* wfrag_ws   = (ushort*)(ws);                           // 131072 B
    float*  bias_part  = (float*) (ws + 131072);                  // 524288 B
    float*  esum_ws    = (float*) (ws + 131072 + 524288);         //   2048 B
    float*  partial_ws = (float*) (ws + 131072 + 524288 + 2048);  // 524288 B

    prep_kernel<<<544, 256, 0, stream>>>(aspect, sentence, context_w, aspect_w, sent_w,
                                         bias_part, wfrag_ws);
    attn_main<<<NBLK, 512, 0, stream>>>(ctx, mask, attend_w, bias_part, wfrag_ws,
                                        partial_ws, esum_ws);
    finalize_kernel<<<BB, 256, 0, stream>>>(sentence, partial_ws, esum_ws, out);
}

// Round 9
// 46.259 us; speedup vs baseline: 3.4188x; 1.0448x over previous
//
#include <hip/hip_runtime.h>
#include <hip/hip_bf16.h>

// Problem dims (fixed by the reference): B=64, T=2048, D=256
#define BB  64
#define TT  2048
#define DD  256
#define EPSV 1e-7f
#define TILE_R 32   // rows per tile
#define NTILE  8    // tiles per block
#define NBLK   512  // blocks: NBLK*NTILE*TILE_R == BB*TT

typedef __attribute__((ext_vector_type(8))) short bf16x8;   // MFMA A/B fragment (4 VGPR)
typedef __attribute__((ext_vector_type(4))) float f32x4;    // MFMA C/D fragment

__device__ __forceinline__ ushort f2bf(float f) {           // RNE (prep only)
    union { float f; unsigned u; } v; v.f = f;
    unsigned u = v.u;
    unsigned r = (u + 0x7FFFu + ((u >> 16) & 1u)) >> 16;
    return (ushort)r;
}

__device__ __forceinline__ float bf2f(unsigned h16) {       // low 16 bits = bf16
    union { unsigned u; float f; } v; v.u = h16 << 16;
    return v.f;
}

// pack two f32 -> two bf16 (round-half-up): [bf(lo), bf(hi)]
__device__ __forceinline__ unsigned pkbf(float lo, float hi) {
    union { float f; unsigned u; } a, b;
    a.f = lo; b.f = hi;
    return __builtin_amdgcn_perm(b.u + 0x8000u, a.u + 0x8000u, 0x07060302u);
}

__device__ __forceinline__ float tanh_fast(float x) {
    float e = __expf(2.0f * x);
    return 1.0f - 2.0f * __builtin_amdgcn_rcpf(e + 1.0f);
}

// sum over the 16-lane DPP row via rotations (pure VALU, no LDS traffic)
template<int CTRL>
__device__ __forceinline__ float dpp_rot_add(float x) {
    union { float f; int i; } a; a.f = x;
    int r = __builtin_amdgcn_update_dpp(0, a.i, CTRL, 0xF, 0xF, true);
    union { int i; float f; } b; b.i = r;
    return x + b.f;
}
__device__ __forceinline__ float row16_sum(float x) {
    x = dpp_rot_add<0x121>(x);   // row_ror:1
    x = dpp_rot_add<0x122>(x);   // row_ror:2
    x = dpp_rot_add<0x124>(x);   // row_ror:4
    x = dpp_rot_add<0x128>(x);   // row_ror:8
    return x;                    // all 16 lanes hold the row sum
}

// ---------------------------------------------------------------------------
// prep: blocks 0..511   -> bias partials (block b*8+q covers d in [q*32, q*32+32))
//       blocks 512..543 -> W_frag: context_w (f32 [256][256]) -> bf16 MFMA B-frag order
// ---------------------------------------------------------------------------
__global__ __launch_bounds__(256) void prep_kernel(
    const float* __restrict__ aspect, const float* __restrict__ sentence,
    const float* __restrict__ context_w, const float* __restrict__ aspect_w,
    const float* __restrict__ sent_w,
    float* __restrict__ bias_part, ushort* __restrict__ wfrag_ws)
{
    const int blk = blockIdx.x, tid = threadIdx.x;
    if (blk < 512) {
        const int b = blk >> 3, q = blk & 7, e = tid;
        float s = 0.f;
        #pragma unroll 4
        for (int dd = 0; dd < 32; ++dd) {
            const int d = q * 32 + dd;
            s = fmaf(aspect[b * DD + d],   aspect_w[d * DD + e], s);
            s = fmaf(sentence[b * DD + d], sent_w[d * DD + e],   s);
        }
        bias_part[blk * DD + e] = s;
    } else {
        const int flat = (blk - 512) * 256 + tid;    // 0..8191
        const int lane = flat & 63;
        const int kn   = flat >> 6;
        const int kk   = kn >> 4;
        const int n    = kn & 15;
        const int krow = kk * 32 + ((lane >> 4) << 3);
        const int col  = n * 16 + (lane & 15);
        bf16x8 v;
        #pragma unroll
        for (int j = 0; j < 8; ++j)
            v[j] = (short)f2bf(context_w[(size_t)(krow + j) * DD + col]);
        *reinterpret_cast<bf16x8*>(wfrag_ws + (size_t)flat * 8) = v;
    }
}

// ---------------------------------------------------------------------------
// attn_main: 512 blocks x 512 thr (8 waves), 8 tiles of 32 rows.
// QUAD-buffered bf16 tiles, ONE barrier per tile, evals+wsum DEFERRED by one
// iteration so the whole barrier period is mutually independent work:
//   [wsum(it-1) | convert(it+1) | loads(it+2) | GEMM(it) | tanh->gpartT] BAR
// NO setprio (m190: hurts lockstep barrier-synced GEMM structures).
// part_d overlaid on bfb[0] after the loop (last bfb[0] read = do_wsum(4)).
// ---------------------------------------------------------------------------
__global__ __launch_bounds__(512, 2) void attn_main(
    const float* __restrict__ ctx, const int* __restrict__ mask,
    const float* __restrict__ attend_w,
    const float* __restrict__ bias_part, const ushort* __restrict__ wfrag_ws,
    float* __restrict__ partial_ws, float* __restrict__ esum_ws)
{
    __shared__ __align__(16) char bfb[4][TILE_R * 512];  // 4 x 16KB, 512B pitch, XOR swizzle
    __shared__ float gpartT[2][8][TILE_R];               // [phase][cg][row]
    __shared__ float bias_lds[256];
    __shared__ float aw_lds[256];
    __shared__ float mask_lds[256];

    const int tid  = threadIdx.x;
    const int wave = tid >> 6;
    const int lane = tid & 63;
    const int blk  = blockIdx.x;
    const int b    = blk >> 3;               // 8 blocks per batch element
    const int cg   = wave;                   // col group (32 cols)
    const int l15  = lane & 15, hi = lane >> 4;

    if (tid < 256) {
        float bs = 0.f;
        #pragma unroll
        for (int q = 0; q < 8; ++q) bs += bias_part[(b * 8 + q) * DD + tid];
        bias_lds[tid] = bs;
    } else {
        const int m = tid - 256;
        aw_lds[m]   = attend_w[m];
        mask_lds[m] = (float)mask[blk * 256 + m];
    }

    // ---- preload this wave's 16 B-fragments (cols cg*32 .. +31): 64 VGPR ----
    bf16x8 Bf[8][2];
    {
        const bf16x8* wf = reinterpret_cast<const bf16x8*>(wfrag_ws);
        #pragma unroll
        for (int kk = 0; kk < 8; ++kk) {
            Bf[kk][0] = wf[(kk * 16 + cg * 2 + 0) * 64 + lane];
            Bf[kk][1] = wf[(kk * 16 + cg * 2 + 1) * 64 + lane];
        }
    }

    const float4* src = reinterpret_cast<const float4*>(ctx);
    const int cc  = tid;                     // 8-float chunk index base
    const int crow0 = cc >> 5,         c80 = cc & 31;
    const int crow1 = (512 + cc) >> 5, c81 = (512 + cc) & 31;

    // ---- prologue: load tile 0, convert -> buf0, issue tile 1 loads ----
    float4 sreg[4];
    {
        const size_t base4 = (size_t)(blk * NTILE) * 2048;
        #pragma unroll
        for (int i = 0; i < 2; ++i) {
            const int c = i * 512 + tid;
            sreg[2 * i + 0] = src[base4 + 2 * c + 0];
            sreg[2 * i + 1] = src[base4 + 2 * c + 1];
        }
        char* dst = bfb[0];
        #pragma unroll
        for (int i = 0; i < 2; ++i) {
            const int row = i ? crow1 : crow0, c8 = i ? c81 : c80;
            uint4 u;
            u.x = pkbf(sreg[2 * i].x,     sreg[2 * i].y);
            u.y = pkbf(sreg[2 * i].z,     sreg[2 * i].w);
            u.z = pkbf(sreg[2 * i + 1].x, sreg[2 * i + 1].y);
            u.w = pkbf(sreg[2 * i + 1].z, sreg[2 * i + 1].w);
            *reinterpret_cast<uint4*>(dst + row * 512 + ((c8 * 16) ^ ((row & 7) << 4))) = u;
        }
        const size_t b1 = (size_t)(blk * NTILE + 1) * 2048;
        #pragma unroll
        for (int i = 0; i < 2; ++i) {
            const int c = i * 512 + tid;
            sreg[2 * i + 0] = src[b1 + 2 * c + 0];
            sreg[2 * i + 1] = src[b1 + 2 * c + 1];
        }
    }
    __syncthreads();

    // loop-invariant epilogue constants
    const int c0 = cg * 32 + l15, c1 = c0 + 16;
    const float bs0 = bias_lds[c0], awc0 = aw_lds[c0];
    const float bs1 = bias_lds[c1], awc1 = aw_lds[c1];

    float accd[4] = {0.f, 0.f, 0.f, 0.f};
    float es_acc = 0.f;

    // deferred evals + weighted sum for tile t (reads gpartT[t&1], bfb[t&3])
    auto do_wsum = [&](int t) {
        const char* pb = bfb[t & 3];
        const int gp = t & 1;
        const int erow = lane & 31;
        float gsum = 0.f;
        #pragma unroll
        for (int c = 0; c < 8; ++c) gsum += gpartT[gp][c][erow];
        const float ev = __expf(gsum) * mask_lds[t * TILE_R + erow];
        es_acc += (lane < 32) ? ev : 0.f;
        #pragma unroll
        for (int rr = 0; rr < 4; ++rr) {
            const int r = wave * 4 + rr;
            const float e = __shfl(ev, r);   // uniform index -> readlane broadcast
            const uint2 hv = *reinterpret_cast<const uint2*>(
                pb + r * 512 + ((lane * 8) ^ ((r & 7) << 4)));
            accd[0] = fmaf(bf2f(hv.x & 0xffffu), e, accd[0]);
            accd[1] = fmaf(bf2f(hv.x >> 16),     e, accd[1]);
            accd[2] = fmaf(bf2f(hv.y & 0xffffu), e, accd[2]);
            accd[3] = fmaf(bf2f(hv.y >> 16),     e, accd[3]);
        }
    };

    for (int it = 0; it < NTILE; ++it) {
        const char* lb = bfb[it & 3];

        // ---- (0) deferred evals+wsum for tile it-1 (independent of this phase) ----
        if (it > 0) do_wsum(it - 1);

        // ---- (1) convert sreg (tile it+1 data) -> buf[(it+1)&3] ----
        if (it + 1 < NTILE) {
            char* dst = bfb[(it + 1) & 3];
            #pragma unroll
            for (int i = 0; i < 2; ++i) {
                const int row = i ? crow1 : crow0, c8 = i ? c81 : c80;
                uint4 u;
                u.x = pkbf(sreg[2 * i].x,     sreg[2 * i].y);
                u.y = pkbf(sreg[2 * i].z,     sreg[2 * i].w);
                u.z = pkbf(sreg[2 * i + 1].x, sreg[2 * i + 1].y);
                u.w = pkbf(sreg[2 * i + 1].z, sreg[2 * i + 1].w);
                *reinterpret_cast<uint4*>(dst + row * 512 + ((c8 * 16) ^ ((row & 7) << 4))) = u;
            }
        }
        // ---- (2) issue tile it+2 global loads ----
        if (it + 2 < NTILE) {
            const size_t base4 = (size_t)(blk * NTILE + it + 2) * 2048;
            #pragma unroll
            for (int i = 0; i < 2; ++i) {
                const int c = i * 512 + tid;
                sreg[2 * i + 0] = src[base4 + 2 * c + 0];
                sreg[2 * i + 1] = src[base4 + 2 * c + 1];
            }
        }

        // ---- (3) GEMM: 32 rows x this wave's 32 cols, K=256 ----
        f32x4 acc[2][2];
        #pragma unroll
        for (int rt = 0; rt < 2; ++rt) {
            acc[rt][0] = (f32x4){0.f, 0.f, 0.f, 0.f};
            acc[rt][1] = (f32x4){0.f, 0.f, 0.f, 0.f};
        }
        #pragma unroll
        for (int rt = 0; rt < 2; ++rt) {
            const int row = rt * 16 + l15;
            const char* ab = lb + row * 512;
            const int asw = (row & 7) << 4;
            #pragma unroll
            for (int kk = 0; kk < 8; ++kk) {
                const bf16x8 a = *reinterpret_cast<const bf16x8*>(
                    ab + ((kk * 64 + (hi << 4)) ^ asw));
                acc[rt][0] = __builtin_amdgcn_mfma_f32_16x16x32_bf16(a, Bf[kk][0], acc[rt][0], 0, 0, 0);
                acc[rt][1] = __builtin_amdgcn_mfma_f32_16x16x32_bf16(a, Bf[kk][1], acc[rt][1], 0, 0, 0);
            }
        }

        // ---- (4) tanh epilogue + DPP reduce -> gpartT[it&1][cg][*] ----
        const int gp = it & 1;
        #pragma unroll
        for (int rt = 0; rt < 2; ++rt) {
            float g0 = row16_sum(tanh_fast(acc[rt][0][0] + bs0) * awc0
                               + tanh_fast(acc[rt][1][0] + bs1) * awc1);
            float g1 = row16_sum(tanh_fast(acc[rt][0][1] + bs0) * awc0
                               + tanh_fast(acc[rt][1][1] + bs1) * awc1);
            float g2 = row16_sum(tanh_fast(acc[rt][0][2] + bs0) * awc0
                               + tanh_fast(acc[rt][1][2] + bs1) * awc1);
            float g3 = row16_sum(tanh_fast(acc[rt][0][3] + bs0) * awc0
                               + tanh_fast(acc[rt][1][3] + bs1) * awc1);
            if (l15 == 0) {
                const int r = rt * 16 + (hi << 2);
                *reinterpret_cast<float4*>(&gpartT[gp][cg][r]) = (float4){g0, g1, g2, g3};
            }
        }
        __syncthreads();   // the ONLY barrier per tile
    }

    // ---- drain: evals+wsum for the last tile ----
    do_wsum(NTILE - 1);

    // ---- block epilogue: part_d overlaid on bfb[0] (dead after do_wsum(4)) ----
    {
        float* part_d = reinterpret_cast<float*>(bfb[0]);    // [8][256]
        *reinterpret_cast<float4*>(&part_d[wave * 256 + lane * 4]) =
            (float4){accd[0], accd[1], accd[2], accd[3]};
    }
    __syncthreads();
    if (tid < 256) {
        const float* part_d = reinterpret_cast<const float*>(bfb[0]);
        float s = 0.f;
        #pragma unroll
        for (int w = 0; w < 8; ++w) s += part_d[w * 256 + tid];
        partial_ws[blk * DD + tid] = s;
    }
    if (wave == 0) {
        float s = row16_sum(es_acc);
        s += __shfl_xor(s, 16);
        if (lane == 0) esum_ws[blk] = s;
    }
}

// ---------------------------------------------------------------------------
// finalize: out[b,d] = (sum_i partial) / (sum_i esum + EPS) + sentence[b,d]
// ---------------------------------------------------------------------------
__global__ __launch_bounds__(256) void finalize_kernel(
    const float* __restrict__ sentence, const float* __restrict__ partial_ws,
    const float* __restrict__ esum_ws, float* __restrict__ out)
{
    const int b = blockIdx.x, d = threadIdx.x;
    float es = 0.f, s = 0.f;
    #pragma unroll
    for (int i = 0; i < 8; ++i) {
        es += esum_ws[b * 8 + i];
        s  += partial_ws[(size_t)(b * 8 + i) * DD + d];
    }
    out[b * DD + d] = s / (es + EPSV) + sentence[b * DD + d];
}

extern "C" void kernel_launch(void* const* d_in, const int* in_sizes, int n_in,
                              void* d_out, int out_size, void* d_ws, size_t ws_size,
                              hipStream_t stream)
{
    const float* ctx       = (const float*)d_in[0];
    const float* aspect    = (const float*)d_in[1];
    const float* sentence  = (const float*)d_in[2];
    const int*   mask      = (const int*)  d_in[3];
    const float* context_w = (const float*)d_in[4];
    const float* aspect_w  = (const float*)d_in[5];
    const float* sent_w    = (const float*)d_in[6];
    const float* attend_w  = (const float*)d_in[7];
    float* out = (float*)d_out;

    char* ws = (char*)d_ws;
    ushort* wfrag_ws   = (ushort*)(ws);                           // 131072 B
    float*  bias_part  = (float*) (ws + 131072);                  // 524288 B
    float*  esum_ws    = (float*) (ws + 131072 + 524288);         //   2048 B
    float*  partial_ws = (float*) (ws + 131072 + 524288 + 2048);  // 524288 B

    prep_kernel<<<544, 256, 0, stream>>>(aspect, sentence, context_w, aspect_w, sent_w,
                                         bias_part, wfrag_ws);
    attn_main<<<NBLK, 512, 0, stream>>>(ctx, mask, attend_w, bias_part, wfrag_ws,
                                        partial_ws, esum_ws);
    finalize_kernel<<<BB, 256, 0, stream>>>(sentence, partial_ws, esum_ws, out);
}